// Round 18
// baseline (151.207 us; speedup 1.0000x reference)
//
#include <hip/hip_runtime.h>

// ECT: ect[b,s,t] = sum_{i: batch[i]==b} sigmoid(lin[s] - <x_i, v_t>)
// N=200000, F=3, T=32, S=32, B=128. Output [B,S,T] f32.
//
// sigmoid(lin - nh) = 1/(1 + E*c), E = exp2(x.(v*log2e)), c = exp(-lin).
// Paired reciprocal: r = rcp(w0*w1) -> sig0 = r*w1, sig1 = r*w0.
//
// r9 structure: TRANSPOSED mapping. Lane = (s_half, t): t = lane&31,
// s_range = (lane>>5)*16 .. +16, 16 accumulators in registers per lane.
// All 64 lanes of a wave process the SAME point -> x reads are wave-uniform
// s_loads (scalar pipe; zero VMEM/LDS in hot loop). Waves stride points 4-way.
// Kills the 8x dot+exp2 redundancy of the old (t,s-group) mapping and gives
// each exp2 ~40 independent FMAs of ILP. Issue floor ~13 us.
// Epilogue: per-segment LDS combine (ds_add) + 4 coalesced global atomics
// per thread (same atomic count as before).

#define CHUNK 64
#define TT 32
#define SS 32
#define LOG2E 1.4426950408889634f

__global__ void zero_out_kernel(float* __restrict__ out, int n) {
    int i = blockIdx.x * blockDim.x + threadIdx.x;
    if (i < n) out[i] = 0.0f;
}

__global__ __launch_bounds__(256, 6) void ect_kernel(
    const float* __restrict__ x, const int* __restrict__ batch,
    const float* __restrict__ v, const float* __restrict__ lin,
    float* __restrict__ out, int N) {
    __shared__ float lds[SS * TT];  // 4 KB block-level accumulator tile

    const int tid  = threadIdx.x;
    const int base = blockIdx.x * CHUNK;
    const int cnt  = min(CHUNK, N - base);
    if (cnt <= 0) return;  // uniform across block (never taken: 3125*64==N)

    // Force wave-uniform wave id so the point loop scalarizes -> s_load.
    const int wid    = __builtin_amdgcn_readfirstlane(tid >> 6);  // 0..3
    const int lane   = tid & 63;
    const int t      = lane & 31;
    const int s_base = (lane >> 5) * 16;  // 0 or 16

    // Zero LDS tile.
    for (int i = tid; i < SS * TT; i += 256) lds[i] = 0.0f;

    // Per-lane constants: direction (pre-scaled by log2e) and c[s] = exp(-lin).
    const float v0 = v[t] * LOG2E;
    const float v1 = v[TT + t] * LOG2E;
    const float v2 = v[2 * TT + t] * LOG2E;
    float c[16];
    #pragma unroll
    for (int si = 0; si < 16; ++si)
        c[si] = __builtin_amdgcn_exp2f(-lin[s_base + si] * LOG2E);

    float acc[16];
    #pragma unroll
    for (int si = 0; si < 16; ++si) acc[si] = 0.0f;

    __syncthreads();  // LDS zeros visible

    const float* __restrict__ xc = x + 3 * (size_t)base;
    const int*   __restrict__ bc = batch + base;

    int j = 0;
    while (j < cnt) {
        const int b = bc[j];  // uniform
        int end;
        if (bc[cnt - 1] == b) {
            end = cnt;  // hot path: rest of chunk is one graph (~96% of blocks)
        } else {
            end = j + 1;
            while (end < cnt && bc[end] == b) ++end;  // uniform scalar scan
        }

        // Accumulate points p in [j,end) with (p & 3) == wid.
        for (int p = j + ((wid - j) & 3); p < end; p += 4) {
            float s0 = xc[3 * p], s1 = xc[3 * p + 1], s2 = xc[3 * p + 2];
            float E  = __builtin_amdgcn_exp2f(fmaf(s2, v2, fmaf(s1, v1, s0 * v0)));
            #pragma unroll
            for (int si = 0; si < 16; si += 2) {
                float w0 = fmaf(E, c[si],     1.0f);
                float w1 = fmaf(E, c[si + 1], 1.0f);
                float r  = __builtin_amdgcn_rcpf(w0 * w1);
                acc[si]     = fmaf(r, w1, acc[si]);
                acc[si + 1] = fmaf(r, w0, acc[si + 1]);
            }
        }

        // Segment flush: registers -> LDS (2 rows of 32 per instr: conflict-free).
        #pragma unroll
        for (int si = 0; si < 16; ++si) {
            atomicAdd(&lds[(s_base + si) * TT + t], acc[si]);
            acc[si] = 0.0f;
        }
        __syncthreads();

        // LDS -> global (coalesced, 4 atomics/thread), re-zero for next segment.
        float* ob = out + b * (SS * TT);
        for (int i = tid; i < SS * TT; i += 256) {
            atomicAdd(&ob[i], lds[i]);
            lds[i] = 0.0f;
        }
        __syncthreads();

        j = end;
    }
}

extern "C" void kernel_launch(void* const* d_in, const int* in_sizes, int n_in,
                              void* d_out, int out_size, void* d_ws, size_t ws_size,
                              hipStream_t stream) {
    const float* x     = (const float*)d_in[0];  // [N,3]
    const int*   batch = (const int*)d_in[1];    // [N]
    const float* v     = (const float*)d_in[2];  // [3,32]
    const float* lin   = (const float*)d_in[3];  // [32]
    float* out = (float*)d_out;                  // [128,32,32]

    const int N = in_sizes[1];

    zero_out_kernel<<<(out_size + 255) / 256, 256, 0, stream>>>(out, out_size);

    const int nblocks = (N + CHUNK - 1) / CHUNK;
    ect_kernel<<<nblocks, 256, 0, stream>>>(x, batch, v, lin, out, N);
}